// Round 3
// baseline (248.286 us; speedup 1.0000x reference)
//
#include <hip/hip_runtime.h>
#include <hip/hip_bf16.h>
#include <math.h>

typedef __bf16 bf16_t;
typedef __bf16 bf8 __attribute__((ext_vector_type(8)));
typedef __bf16 bf4 __attribute__((ext_vector_type(4)));
typedef __bf16 bf16x2 __attribute__((ext_vector_type(2)));
typedef float f32x4 __attribute__((ext_vector_type(4)));

#define AS1 __attribute__((address_space(1)))
#define AS3 __attribute__((address_space(3)))

#define B_ROWS 4096
#define NTOT   8192
#define DIN    1024
#define DENC   512
#define DH     256
#define DP     128
#define INV_T        14.285714285714286f   // 1/0.07
#define SCALE_LOG2   20.609929155556620f   // log2(e)/0.07

__device__ __forceinline__ f32x4 mfma_16x16x32(bf8 a, bf8 b, f32x4 c) {
  return __builtin_amdgcn_mfma_f32_16x16x32_bf16(a, b, c, 0, 0, 0);
}

// ---------------------------------------------------------------------------
// prep: ONE dispatch. Blocks 0..335: LDS-tiled weight transpose [K][N] f32 ->
// [N][K] bf16 (coalesced both sides). Blocks 336+: x f32->bf16 cast, float4.
// ---------------------------------------------------------------------------
__global__ __launch_bounds__(256) void prep_kernel(
    const float* __restrict__ x_i, const float* __restrict__ x_t,
    const float* __restrict__ We_i, const float* __restrict__ We_t,
    const float* __restrict__ W1_i, const float* __restrict__ W1_t,
    const float* __restrict__ W2_i, const float* __restrict__ W2_t,
    bf16_t* __restrict__ xb_i, bf16_t* __restrict__ xb_t,
    bf16_t* __restrict__ Wet_i, bf16_t* __restrict__ Wet_t,
    bf16_t* __restrict__ W1t_i, bf16_t* __restrict__ W1t_t,
    bf16_t* __restrict__ W2t_i, bf16_t* __restrict__ W2t_t) {
  const int b = blockIdx.x;
  const int tid = threadIdx.x;
  if (b >= 336) {                          // ---- cast path
    int idx = (b - 336) * 256 + tid;       // 0 .. 2*1048576-1
    const int HALF = (B_ROWS * DIN) / 4;
    const float* s; bf16_t* d; int off;
    if (idx < HALF) { s = x_i; d = xb_i; off = idx; }
    else            { s = x_t; d = xb_t; off = idx - HALF; }
    float4 v = ((const float4*)s)[off];
    bf4 w = { (bf16_t)v.x, (bf16_t)v.y, (bf16_t)v.z, (bf16_t)v.w };
    ((bf4*)d)[off] = w;
    return;
  }
  // ---- transpose path
  const float* src; bf16_t* dst; int K, N, tile;
  if (b < 128)      { src = We_i; dst = Wet_i; K = 1024; N = 512; tile = b; }
  else if (b < 256) { src = We_t; dst = Wet_t; K = 1024; N = 512; tile = b - 128; }
  else if (b < 288) { src = W1_i; dst = W1t_i; K = 512;  N = 256; tile = b - 256; }
  else if (b < 320) { src = W1_t; dst = W1t_t; K = 512;  N = 256; tile = b - 288; }
  else if (b < 328) { src = W2_i; dst = W2t_i; K = 256;  N = 128; tile = b - 320; }
  else              { src = W2_t; dst = W2t_t; K = 256;  N = 128; tile = b - 328; }
  const int tilesN = N >> 6;
  const int k0 = (tile / tilesN) * 64;
  const int n0 = (tile % tilesN) * 64;

  __shared__ float ld[64][65];
  #pragma unroll
  for (int i = 0; i < 4; ++i) {
    int cid = tid + i * 256;
    int r = cid >> 4;
    int c = (cid & 15) * 4;
    float4 v = *(const float4*)(src + (size_t)(k0 + r) * N + n0 + c);
    ld[r][c + 0] = v.x; ld[r][c + 1] = v.y; ld[r][c + 2] = v.z; ld[r][c + 3] = v.w;
  }
  __syncthreads();
  #pragma unroll
  for (int i = 0; i < 2; ++i) {
    int cid = tid + i * 256;
    int rn = cid >> 3;
    int c8 = (cid & 7) * 8;
    bf8 w;
    #pragma unroll
    for (int j = 0; j < 8; ++j) w[j] = (bf16_t)ld[c8 + j][rn];
    *(bf8*)(dst + (size_t)(n0 + rn) * K + k0 + c8) = w;
  }
}

// ---------------------------------------------------------------------------
// gemm_glds: m97-style GEMM with async global->LDS staging (width=16).
// Tile: MT x 64, BK=32, 256 threads (4 waves). MT=128: wave = 2x16 rows;
// MT=64: wave = 16 rows. Single LDS buffer, 2-barrier K-loop.
// LDS layout [row][32] contiguous (glds constraint: lane-contiguous 16B).
// Paired img/txt via blockIdx.z.
// ---------------------------------------------------------------------------
template<int MT, bool RELU>
__global__ __launch_bounds__(256) void gemm_glds(
    const bf16_t* __restrict__ A0, const bf16_t* __restrict__ A1,
    const bf16_t* __restrict__ B0, const bf16_t* __restrict__ B1,
    const float* __restrict__ bias0, const float* __restrict__ bias1,
    bf16_t* __restrict__ out0, bf16_t* __restrict__ out1,
    int N, int K) {
  const bf16_t* A   = blockIdx.z ? A1 : A0;
  const bf16_t* Bt  = blockIdx.z ? B1 : B0;
  const float* bias = blockIdx.z ? bias1 : bias0;
  bf16_t* outp      = blockIdx.z ? out1 : out0;

  const int nb   = blockIdx.x * 64;
  const int mb   = blockIdx.y * MT;
  const int tid  = threadIdx.x;
  const int wave = tid >> 6;
  const int lane = tid & 63;
  const int l15  = lane & 15;
  const int quad = lane >> 4;
  constexpr int CH = MT / 64;            // row-chains per wave

  __shared__ __align__(16) bf16_t As[MT * 32];
  __shared__ __align__(16) bf16_t Bs[64 * 32];

  f32x4 acc[CH][4];
  #pragma unroll
  for (int i = 0; i < CH; ++i)
    #pragma unroll
    for (int j = 0; j < 4; ++j) acc[i][j] = (f32x4){0.f, 0.f, 0.f, 0.f};

  for (int k0 = 0; k0 < K; k0 += 32) {
    __syncthreads();                     // prev-step LDS reads complete
    #pragma unroll
    for (int i = 0; i < CH; ++i) {       // stage A: MT*4 slots of 16B
      const int s = tid + i * 256;
      const bf16_t* ga = A + (size_t)(mb + (s >> 2)) * K + k0 + (s & 3) * 8;
      __builtin_amdgcn_global_load_lds(
          (const AS1 void*)ga,
          (AS3 void*)(As + (size_t)(wave * 64 + i * 256) * 8), 16, 0, 0);
    }
    {                                    // stage B: 256 slots of 16B
      const int s = tid;
      const bf16_t* gb = Bt + (size_t)(nb + (s >> 2)) * K + k0 + (s & 3) * 8;
      __builtin_amdgcn_global_load_lds(
          (const AS1 void*)gb,
          (AS3 void*)(Bs + (size_t)(wave * 64) * 8), 16, 0, 0);
    }
    __syncthreads();                     // staged data visible (vmcnt drained)

    bf8 a[CH];
    #pragma unroll
    for (int i = 0; i < CH; ++i)
      a[i] = *(const bf8*)(As + (size_t)(wave * (16 * CH) + i * 16 + l15) * 32 + quad * 8);
    #pragma unroll
    for (int nt = 0; nt < 4; ++nt) {
      bf8 bb = *(const bf8*)(Bs + (size_t)(nt * 16 + l15) * 32 + quad * 8);
      #pragma unroll
      for (int i = 0; i < CH; ++i)
        acc[i][nt] = mfma_16x16x32(a[i], bb, acc[i][nt]);
    }
  }

  #pragma unroll
  for (int i = 0; i < CH; ++i) {
    const int orow = mb + wave * (16 * CH) + i * 16 + quad * 4;
    #pragma unroll
    for (int nt = 0; nt < 4; ++nt) {
      const int ocol = nb + nt * 16 + l15;
      const float bval = bias[ocol];
      #pragma unroll
      for (int r = 0; r < 4; ++r) {
        float v = acc[i][nt][r] + bval;
        if (RELU) v = fmaxf(v, 0.f);
        outp[(size_t)(orow + r) * N + ocol] = (bf16_t)v;
      }
    }
  }
}

// ---------------------------------------------------------------------------
// head2_norm: paired z = g @ W2t^T + b2 (K=256, N=128) with fused L2 norm;
// emits bf16 reps directly.
// ---------------------------------------------------------------------------
__global__ __launch_bounds__(256) void head2_norm(
    const bf16_t* __restrict__ A0, const bf16_t* __restrict__ A1,
    const bf16_t* __restrict__ B0, const bf16_t* __restrict__ B1,
    const float* __restrict__ bias0, const float* __restrict__ bias1,
    bf16_t* __restrict__ reps) {
  const bf16_t* A   = blockIdx.z ? A1 : A0;
  const bf16_t* Bt  = blockIdx.z ? B1 : B0;
  const float* bias = blockIdx.z ? bias1 : bias0;

  const int mb   = blockIdx.x * 64;
  const int tid  = threadIdx.x;
  const int wave = tid >> 6;
  const int lane = tid & 63;
  const int l15  = lane & 15;
  const int quad = lane >> 4;

  __shared__ __align__(16) bf16_t As[64][40];
  __shared__ __align__(16) bf16_t Bs[128][40];

  f32x4 acc[8];
  #pragma unroll
  for (int i = 0; i < 8; ++i) acc[i] = (f32x4){0.f, 0.f, 0.f, 0.f};

  const int arow   = tid >> 2;
  const int achunk = (tid & 3) << 3;
  const bf16_t* Ap = A + (size_t)(mb + arow) * DH + achunk;

  for (int k0 = 0; k0 < DH; k0 += 32) {
    uint4 av = *(const uint4*)(Ap + k0);
    uint4 bv[2];
    #pragma unroll
    for (int i = 0; i < 2; ++i) {
      int cid = tid + i * 256;
      int br = cid >> 2, bc = (cid & 3) << 3;
      bv[i] = *(const uint4*)(Bt + (size_t)br * DH + k0 + bc);
    }
    __syncthreads();
    *(uint4*)&As[arow][achunk] = av;
    #pragma unroll
    for (int i = 0; i < 2; ++i) {
      int cid = tid + i * 256;
      int br = cid >> 2, bc = (cid & 3) << 3;
      *(uint4*)&Bs[br][bc] = bv[i];
    }
    __syncthreads();
    bf8 af = *(const bf8*)&As[wave * 16 + l15][quad * 8];
    #pragma unroll
    for (int nt = 0; nt < 8; ++nt) {
      bf8 bfv = *(const bf8*)&Bs[nt * 16 + l15][quad * 8];
      acc[nt] = mfma_16x16x32(af, bfv, acc[nt]);
    }
  }

  #pragma unroll
  for (int nt = 0; nt < 8; ++nt) {
    const float bval = bias[nt * 16 + l15];
    #pragma unroll
    for (int r = 0; r < 4; ++r) acc[nt][r] += bval;
  }
  const size_t rowbase = (size_t)(blockIdx.z ? B_ROWS : 0) + mb + wave * 16 + quad * 4;
  #pragma unroll
  for (int r = 0; r < 4; ++r) {
    float ss = 0.f;
    #pragma unroll
    for (int nt = 0; nt < 8; ++nt) ss += acc[nt][r] * acc[nt][r];
    ss += __shfl_xor(ss, 1);
    ss += __shfl_xor(ss, 2);
    ss += __shfl_xor(ss, 4);
    ss += __shfl_xor(ss, 8);
    const float inv = 1.0f / fmaxf(sqrtf(ss), 1e-12f);
    #pragma unroll
    for (int nt = 0; nt < 8; ++nt)
      reps[(rowbase + r) * DP + nt * 16 + l15] = (bf16_t)(acc[nt][r] * inv);
  }
}

// ---------------------------------------------------------------------------
// sim_rowsum: fused reps·repsᵀ + unweighted exp row-sums, register software
// pipeline (depth 2) over fully-unrolled 16-col tiles so B-frag L2 latency
// overlaps MFMA+exp of earlier tiles. Wave = 2 row-chains of 16 (2x ILP).
// Grid (32 col-slices x 64 row-blocks of 128) = 2048 WGs.
// ---------------------------------------------------------------------------
__global__ __launch_bounds__(256, 3) void sim_rowsum_kernel(
    const bf16_t* __restrict__ reps, float* __restrict__ S) {
  const int rowbase = blockIdx.y * 128;
  const int col0    = blockIdx.x * 256;
  const int tid  = threadIdx.x;
  const int wave = tid >> 6;
  const int lane = tid & 63;
  const int l15  = lane & 15;
  const int quad = lane >> 4;

  const int r0 = rowbase + wave * 32;
  bf8 af0[4], af1[4];
  #pragma unroll
  for (int kt = 0; kt < 4; ++kt) {
    af0[kt] = *(const bf8*)(reps + (size_t)(r0 + l15)      * DP + kt * 32 + quad * 8);
    af1[kt] = *(const bf8*)(reps + (size_t)(r0 + 16 + l15) * DP + kt * 32 + quad * 8);
  }

  float rs0[4] = {0.f, 0.f, 0.f, 0.f};
  float rs1[4] = {0.f, 0.f, 0.f, 0.f};

  const bf16_t* bbase = reps + (size_t)(col0 + l15) * DP + quad * 8;

  bf8 buf[3][4];
  auto loadB = [&](int t, bf8* dst) {
    const bf16_t* p = bbase + (size_t)t * 16 * DP;
    dst[0] = *(const bf8*)(p);
    dst[1] = *(const bf8*)(p + 32);
    dst[2] = *(const bf8*)(p + 64);
    dst[3] = *(const bf8*)(p + 96);
  };
  loadB(0, buf[0]);
  loadB(1, buf[1]);

  #pragma unroll
  for (int t = 0; t < 16; ++t) {
    if (t + 2 < 16) loadB(t + 2, buf[(t + 2) % 3]);
    const bf8* b = buf[t % 3];
    f32x4 acc0 = (f32x4){0.f, 0.f, 0.f, 0.f};
    f32x4 acc1 = (f32x4){0.f, 0.f, 0.f, 0.f};
    acc0 = mfma_16x16x32(af0[0], b[0], acc0); acc1 = mfma_16x16x32(af1[0], b[0], acc1);
    acc0 = mfma_16x16x32(af0[1], b[1], acc0); acc1 = mfma_16x16x32(af1[1], b[1], acc1);
    acc0 = mfma_16x16x32(af0[2], b[2], acc0); acc1 = mfma_16x16x32(af1[2], b[2], acc1);
    acc0 = mfma_16x16x32(af0[3], b[3], acc0); acc1 = mfma_16x16x32(af1[3], b[3], acc1);
    #pragma unroll
    for (int r = 0; r < 4; ++r) {
      rs0[r] += __builtin_amdgcn_exp2f(acc0[r] * SCALE_LOG2);
      rs1[r] += __builtin_amdgcn_exp2f(acc1[r] * SCALE_LOG2);
    }
  }

  const int i0 = r0 + quad * 4;
  #pragma unroll
  for (int r = 0; r < 4; ++r) {
    float v = rs0[r];
    v += __shfl_xor(v, 1); v += __shfl_xor(v, 2);
    v += __shfl_xor(v, 4); v += __shfl_xor(v, 8);
    if (l15 == 0) atomicAdd(&S[i0 + r], v);
  }
  #pragma unroll
  for (int r = 0; r < 4; ++r) {
    float v = rs1[r];
    v += __shfl_xor(v, 1); v += __shfl_xor(v, 2);
    v += __shfl_xor(v, 4); v += __shfl_xor(v, 8);
    if (l15 == 0) atomicAdd(&S[i0 + 16 + r], v);
  }
}

// ---------------------------------------------------------------------------
// rowfinal: per-row loss correction + grid-wide mean via device-scope atomic
// finalize (last block writes d_out). 128 blocks x 256; wave handles 16 rows.
//   L_i = log(S_raw - exp(d_ii/t) + exp(pos/t)) - pos/t
// ---------------------------------------------------------------------------
__global__ __launch_bounds__(256) void rowfinal_kernel(
    const bf16_t* __restrict__ reps, const float* __restrict__ S,
    float* __restrict__ Lsum, int* __restrict__ cnt,
    float* __restrict__ out) {
  const int tid  = threadIdx.x;
  const int wave = tid >> 6;
  const int lane = tid & 63;
  float part = 0.f;
  #pragma unroll 1
  for (int i = 0; i < 16; ++i) {
    const int row = blockIdx.x * 64 + wave * 16 + i;
    bf16x2 a = *(const bf16x2*)(reps + (size_t)row * DP + lane * 2);
    bf16x2 b = *(const bf16x2*)(reps + (size_t)(row ^ B_ROWS) * DP + lane * 2);
    float a0 = (float)a.x, a1 = (float)a.y;
    float b0 = (float)b.x, b1 = (float)b.y;
    float dii = a0 * a0 + a1 * a1;
    float pos = a0 * b0 + a1 * b1;
    #pragma unroll
    for (int m = 1; m < 64; m <<= 1) {
      dii += __shfl_xor(dii, m);
      pos += __shfl_xor(pos, m);
    }
    if (lane == 0) {
      float Si = S[row] - __builtin_amdgcn_exp2f(dii * SCALE_LOG2)
                        + __builtin_amdgcn_exp2f(pos * SCALE_LOG2);
      part += logf(Si) - pos * INV_T;
    }
  }
  __shared__ float wpart[4];
  if (lane == 0) wpart[wave] = part;
  __syncthreads();
  if (tid == 0) {
    float bsum = wpart[0] + wpart[1] + wpart[2] + wpart[3];
    atomicAdd(Lsum, bsum);
    __threadfence();
    int old = __hip_atomic_fetch_add(cnt, 1, __ATOMIC_ACQ_REL,
                                     __HIP_MEMORY_SCOPE_AGENT);
    if (old == (int)gridDim.x - 1) {
      float tot = __hip_atomic_load(Lsum, __ATOMIC_RELAXED,
                                    __HIP_MEMORY_SCOPE_AGENT);
      out[0] = tot * (1.0f / NTOT);
    }
  }
}

// ---------------------------------------------------------------------------
extern "C" void kernel_launch(void* const* d_in, const int* in_sizes, int n_in,
                              void* d_out, int out_size, void* d_ws, size_t ws_size,
                              hipStream_t stream) {
  const float* x_img  = (const float*)d_in[0];
  const float* x_txt  = (const float*)d_in[1];
  const float* We_img = (const float*)d_in[2];
  const float* be_img = (const float*)d_in[3];
  const float* We_txt = (const float*)d_in[4];
  const float* be_txt = (const float*)d_in[5];
  const float* W1_img = (const float*)d_in[6];
  const float* b1_img = (const float*)d_in[7];
  const float* W2_img = (const float*)d_in[8];
  const float* b2_img = (const float*)d_in[9];
  const float* W1_txt = (const float*)d_in[10];
  const float* b1_txt = (const float*)d_in[11];
  const float* W2_txt = (const float*)d_in[12];
  const float* b2_txt = (const float*)d_in[13];

  char* p = (char*)d_ws;
  bf16_t* xbf_img = (bf16_t*)p; p += (size_t)B_ROWS * DIN * 2;
  bf16_t* xbf_txt = (bf16_t*)p; p += (size_t)B_ROWS * DIN * 2;
  bf16_t* Wet_img = (bf16_t*)p; p += (size_t)DENC * DIN * 2;
  bf16_t* Wet_txt = (bf16_t*)p; p += (size_t)DENC * DIN * 2;
  bf16_t* W1t_img = (bf16_t*)p; p += (size_t)DH * DENC * 2;
  bf16_t* W1t_txt = (bf16_t*)p; p += (size_t)DH * DENC * 2;
  bf16_t* W2t_img = (bf16_t*)p; p += (size_t)DP * DH * 2;
  bf16_t* W2t_txt = (bf16_t*)p; p += (size_t)DP * DH * 2;
  bf16_t* h_img   = (bf16_t*)p; p += (size_t)B_ROWS * DENC * 2;
  bf16_t* h_txt   = (bf16_t*)p; p += (size_t)B_ROWS * DENC * 2;
  bf16_t* g_img   = (bf16_t*)p; p += (size_t)B_ROWS * DH * 2;
  bf16_t* g_txt   = (bf16_t*)p; p += (size_t)B_ROWS * DH * 2;
  bf16_t* reps    = (bf16_t*)p; p += (size_t)NTOT * DP * 2;
  float*  S       = (float*) p; p += (size_t)NTOT * 4;
  float*  Lsum    = (float*) p; p += 4;
  int*    cnt     = (int*)   p; p += 4;

  // zero S + Lsum + cnt in one memset
  hipMemsetAsync(S, 0, (size_t)NTOT * 4 + 8, stream);

  prep_kernel<<<336 + 8192, 256, 0, stream>>>(
      x_img, x_txt, We_img, We_txt, W1_img, W1_txt, W2_img, W2_txt,
      xbf_img, xbf_txt, Wet_img, Wet_txt, W1t_img, W1t_txt, W2t_img, W2t_txt);

  // encoder: h = x @ We + be   [4096x512], K=1024 (img & txt via z)
  gemm_glds<128, false><<<dim3(DENC / 64, B_ROWS / 128, 2), 256, 0, stream>>>(
      xbf_img, xbf_txt, Wet_img, Wet_txt, be_img, be_txt, h_img, h_txt,
      DENC, DIN);
  // head 1: g = relu(h @ W1 + b1)   [4096x256], K=512
  gemm_glds<64, true><<<dim3(DH / 64, B_ROWS / 64, 2), 256, 0, stream>>>(
      h_img, h_txt, W1t_img, W1t_txt, b1_img, b1_txt, g_img, g_txt,
      DH, DENC);
  // head 2 + normalize fused -> reps bf16 [8192x128]
  head2_norm<<<dim3(B_ROWS / 64, 1, 2), 256, 0, stream>>>(
      g_img, g_txt, W2t_img, W2t_txt, b2_img, b2_txt, reps);

  sim_rowsum_kernel<<<dim3(32, NTOT / 128), 256, 0, stream>>>(reps, S);
  rowfinal_kernel<<<NTOT / 64, 256, 0, stream>>>(reps, S, Lsum, cnt,
                                                 (float*)d_out);
}

// Round 4
// 191.844 us; speedup vs baseline: 1.2942x; 1.2942x over previous
//
#include <hip/hip_runtime.h>
#include <hip/hip_bf16.h>
#include <math.h>

typedef __bf16 bf16_t;
typedef __bf16 bf8 __attribute__((ext_vector_type(8)));
typedef __bf16 bf4 __attribute__((ext_vector_type(4)));
typedef __bf16 bf16x2 __attribute__((ext_vector_type(2)));
typedef float f32x4 __attribute__((ext_vector_type(4)));

#define AS1 __attribute__((address_space(1)))
#define AS3 __attribute__((address_space(3)))

#define B_ROWS 4096
#define NTOT   8192
#define DIN    1024
#define DENC   512
#define DH     256
#define DP     128
#define INV_T        14.285714285714286f   // 1/0.07
#define SCALE_LOG2   20.609929155556620f   // log2(e)/0.07

__device__ __forceinline__ f32x4 mfma_16x16x32(bf8 a, bf8 b, f32x4 c) {
  return __builtin_amdgcn_mfma_f32_16x16x32_bf16(a, b, c, 0, 0, 0);
}

// ---------------------------------------------------------------------------
// prep: ONE dispatch. Blocks 0..335: LDS-tiled weight transpose [K][N] f32 ->
// [N][K] bf16 (coalesced both sides). Blocks 336+: x f32->bf16 cast, float4.
// ---------------------------------------------------------------------------
__global__ __launch_bounds__(256) void prep_kernel(
    const float* __restrict__ x_i, const float* __restrict__ x_t,
    const float* __restrict__ We_i, const float* __restrict__ We_t,
    const float* __restrict__ W1_i, const float* __restrict__ W1_t,
    const float* __restrict__ W2_i, const float* __restrict__ W2_t,
    bf16_t* __restrict__ xb_i, bf16_t* __restrict__ xb_t,
    bf16_t* __restrict__ Wet_i, bf16_t* __restrict__ Wet_t,
    bf16_t* __restrict__ W1t_i, bf16_t* __restrict__ W1t_t,
    bf16_t* __restrict__ W2t_i, bf16_t* __restrict__ W2t_t) {
  const int b = blockIdx.x;
  const int tid = threadIdx.x;
  if (b >= 336) {                          // ---- cast path
    int idx = (b - 336) * 256 + tid;       // 0 .. 2*1048576-1
    const int HALF = (B_ROWS * DIN) / 4;
    const float* s; bf16_t* d; int off;
    if (idx < HALF) { s = x_i; d = xb_i; off = idx; }
    else            { s = x_t; d = xb_t; off = idx - HALF; }
    float4 v = ((const float4*)s)[off];
    bf4 w = { (bf16_t)v.x, (bf16_t)v.y, (bf16_t)v.z, (bf16_t)v.w };
    ((bf4*)d)[off] = w;
    return;
  }
  // ---- transpose path
  const float* src; bf16_t* dst; int K, N, tile;
  if (b < 128)      { src = We_i; dst = Wet_i; K = 1024; N = 512; tile = b; }
  else if (b < 256) { src = We_t; dst = Wet_t; K = 1024; N = 512; tile = b - 128; }
  else if (b < 288) { src = W1_i; dst = W1t_i; K = 512;  N = 256; tile = b - 256; }
  else if (b < 320) { src = W1_t; dst = W1t_t; K = 512;  N = 256; tile = b - 288; }
  else if (b < 328) { src = W2_i; dst = W2t_i; K = 256;  N = 128; tile = b - 320; }
  else              { src = W2_t; dst = W2t_t; K = 256;  N = 128; tile = b - 328; }
  const int tilesN = N >> 6;
  const int k0 = (tile / tilesN) * 64;
  const int n0 = (tile % tilesN) * 64;

  __shared__ float ld[64][65];
  #pragma unroll
  for (int i = 0; i < 4; ++i) {
    int cid = tid + i * 256;
    int r = cid >> 4;
    int c = (cid & 15) * 4;
    float4 v = *(const float4*)(src + (size_t)(k0 + r) * N + n0 + c);
    ld[r][c + 0] = v.x; ld[r][c + 1] = v.y; ld[r][c + 2] = v.z; ld[r][c + 3] = v.w;
  }
  __syncthreads();
  #pragma unroll
  for (int i = 0; i < 2; ++i) {
    int cid = tid + i * 256;
    int rn = cid >> 3;
    int c8 = (cid & 7) * 8;
    bf8 w;
    #pragma unroll
    for (int j = 0; j < 8; ++j) w[j] = (bf16_t)ld[c8 + j][rn];
    *(bf8*)(dst + (size_t)(n0 + rn) * K + k0 + c8) = w;
  }
}

// ---------------------------------------------------------------------------
// gemm_glds: m97-style GEMM with async global->LDS staging (width=16).
// Tile: MT x 64, BK=32, 256 threads (4 waves). Single LDS buffer,
// 2-barrier K-loop. Paired img/txt via blockIdx.z.
// ---------------------------------------------------------------------------
template<int MT, bool RELU>
__global__ __launch_bounds__(256) void gemm_glds(
    const bf16_t* __restrict__ A0, const bf16_t* __restrict__ A1,
    const bf16_t* __restrict__ B0, const bf16_t* __restrict__ B1,
    const float* __restrict__ bias0, const float* __restrict__ bias1,
    bf16_t* __restrict__ out0, bf16_t* __restrict__ out1,
    int N, int K) {
  const bf16_t* A   = blockIdx.z ? A1 : A0;
  const bf16_t* Bt  = blockIdx.z ? B1 : B0;
  const float* bias = blockIdx.z ? bias1 : bias0;
  bf16_t* outp      = blockIdx.z ? out1 : out0;

  const int nb   = blockIdx.x * 64;
  const int mb   = blockIdx.y * MT;
  const int tid  = threadIdx.x;
  const int wave = tid >> 6;
  const int lane = tid & 63;
  const int l15  = lane & 15;
  const int quad = lane >> 4;
  constexpr int CH = MT / 64;            // row-chains per wave

  __shared__ __align__(16) bf16_t As[MT * 32];
  __shared__ __align__(16) bf16_t Bs[64 * 32];

  f32x4 acc[CH][4];
  #pragma unroll
  for (int i = 0; i < CH; ++i)
    #pragma unroll
    for (int j = 0; j < 4; ++j) acc[i][j] = (f32x4){0.f, 0.f, 0.f, 0.f};

  for (int k0 = 0; k0 < K; k0 += 32) {
    __syncthreads();
    #pragma unroll
    for (int i = 0; i < CH; ++i) {
      const int s = tid + i * 256;
      const bf16_t* ga = A + (size_t)(mb + (s >> 2)) * K + k0 + (s & 3) * 8;
      __builtin_amdgcn_global_load_lds(
          (const AS1 void*)ga,
          (AS3 void*)(As + (size_t)(wave * 64 + i * 256) * 8), 16, 0, 0);
    }
    {
      const int s = tid;
      const bf16_t* gb = Bt + (size_t)(nb + (s >> 2)) * K + k0 + (s & 3) * 8;
      __builtin_amdgcn_global_load_lds(
          (const AS1 void*)gb,
          (AS3 void*)(Bs + (size_t)(wave * 64) * 8), 16, 0, 0);
    }
    __syncthreads();

    bf8 a[CH];
    #pragma unroll
    for (int i = 0; i < CH; ++i)
      a[i] = *(const bf8*)(As + (size_t)(wave * (16 * CH) + i * 16 + l15) * 32 + quad * 8);
    #pragma unroll
    for (int nt = 0; nt < 4; ++nt) {
      bf8 bb = *(const bf8*)(Bs + (size_t)(nt * 16 + l15) * 32 + quad * 8);
      #pragma unroll
      for (int i = 0; i < CH; ++i)
        acc[i][nt] = mfma_16x16x32(a[i], bb, acc[i][nt]);
    }
  }

  #pragma unroll
  for (int i = 0; i < CH; ++i) {
    const int orow = mb + wave * (16 * CH) + i * 16 + quad * 4;
    #pragma unroll
    for (int nt = 0; nt < 4; ++nt) {
      const int ocol = nb + nt * 16 + l15;
      const float bval = bias[ocol];
      #pragma unroll
      for (int r = 0; r < 4; ++r) {
        float v = acc[i][nt][r] + bval;
        if (RELU) v = fmaxf(v, 0.f);
        outp[(size_t)(orow + r) * N + ocol] = (bf16_t)v;
      }
    }
  }
}

// ---------------------------------------------------------------------------
// head2_norm: paired z = g @ W2t^T + b2 (K=256, N=128) with fused L2 norm;
// emits bf16 reps directly.
// ---------------------------------------------------------------------------
__global__ __launch_bounds__(256) void head2_norm(
    const bf16_t* __restrict__ A0, const bf16_t* __restrict__ A1,
    const bf16_t* __restrict__ B0, const bf16_t* __restrict__ B1,
    const float* __restrict__ bias0, const float* __restrict__ bias1,
    bf16_t* __restrict__ reps) {
  const bf16_t* A   = blockIdx.z ? A1 : A0;
  const bf16_t* Bt  = blockIdx.z ? B1 : B0;
  const float* bias = blockIdx.z ? bias1 : bias0;

  const int mb   = blockIdx.x * 64;
  const int tid  = threadIdx.x;
  const int wave = tid >> 6;
  const int lane = tid & 63;
  const int l15  = lane & 15;
  const int quad = lane >> 4;

  __shared__ __align__(16) bf16_t As[64][40];
  __shared__ __align__(16) bf16_t Bs[128][40];

  f32x4 acc[8];
  #pragma unroll
  for (int i = 0; i < 8; ++i) acc[i] = (f32x4){0.f, 0.f, 0.f, 0.f};

  const int arow   = tid >> 2;
  const int achunk = (tid & 3) << 3;
  const bf16_t* Ap = A + (size_t)(mb + arow) * DH + achunk;

  for (int k0 = 0; k0 < DH; k0 += 32) {
    uint4 av = *(const uint4*)(Ap + k0);
    uint4 bv[2];
    #pragma unroll
    for (int i = 0; i < 2; ++i) {
      int cid = tid + i * 256;
      int br = cid >> 2, bc = (cid & 3) << 3;
      bv[i] = *(const uint4*)(Bt + (size_t)br * DH + k0 + bc);
    }
    __syncthreads();
    *(uint4*)&As[arow][achunk] = av;
    #pragma unroll
    for (int i = 0; i < 2; ++i) {
      int cid = tid + i * 256;
      int br = cid >> 2, bc = (cid & 3) << 3;
      *(uint4*)&Bs[br][bc] = bv[i];
    }
    __syncthreads();
    bf8 af = *(const bf8*)&As[wave * 16 + l15][quad * 8];
    #pragma unroll
    for (int nt = 0; nt < 8; ++nt) {
      bf8 bfv = *(const bf8*)&Bs[nt * 16 + l15][quad * 8];
      acc[nt] = mfma_16x16x32(af, bfv, acc[nt]);
    }
  }

  #pragma unroll
  for (int nt = 0; nt < 8; ++nt) {
    const float bval = bias[nt * 16 + l15];
    #pragma unroll
    for (int r = 0; r < 4; ++r) acc[nt][r] += bval;
  }
  const size_t rowbase = (size_t)(blockIdx.z ? B_ROWS : 0) + mb + wave * 16 + quad * 4;
  #pragma unroll
  for (int r = 0; r < 4; ++r) {
    float ss = 0.f;
    #pragma unroll
    for (int nt = 0; nt < 8; ++nt) ss += acc[nt][r] * acc[nt][r];
    ss += __shfl_xor(ss, 1);
    ss += __shfl_xor(ss, 2);
    ss += __shfl_xor(ss, 4);
    ss += __shfl_xor(ss, 8);
    const float inv = 1.0f / fmaxf(sqrtf(ss), 1e-12f);
    #pragma unroll
    for (int nt = 0; nt < 8; ++nt)
      reps[(rowbase + r) * DP + nt * 16 + l15] = (bf16_t)(acc[nt][r] * inv);
  }
}

// ---------------------------------------------------------------------------
// sim_rowsum: fused reps·repsᵀ + unweighted exp row-sums, LDS-staged B.
// WG = 128 rows x 512-col slice; K-loop over 8 tiles of 64 cols (16 KB each,
// CONTIGUOUS in reps), double-buffered, staged via global_load_lds width=16
// shared by all 4 waves (4x less global B traffic, no per-iter VGPR latency).
// glds forbids padding -> XOR chunk swizzle: 16-B chunk c of column col is
// stored at slot (c ^ (col&15)); staging covers the same contiguous bytes
// (coalescing intact) and ds_read_b128 fragment reads land 2 lanes/bank
// group = conflict-free (m136: 2-way free).
// Wave = 2 row-chains of 16; A-frags in registers for the whole sweep.
// sim<=1 -> sums < 1.4e10, fp32-safe without online max.
// ---------------------------------------------------------------------------
__global__ __launch_bounds__(256) void sim_rowsum_kernel(
    const bf16_t* __restrict__ reps, float* __restrict__ S) {
  const int rowbase = blockIdx.y * 128;
  const int col0    = blockIdx.x * 512;
  const int tid  = threadIdx.x;
  const int wave = tid >> 6;
  const int lane = tid & 63;
  const int l15  = lane & 15;
  const int quad = lane >> 4;

  __shared__ __align__(16) bf16_t Bs[2][64 * DP];   // 2 x 16 KB

  const int r0 = rowbase + wave * 32;
  bf8 af0[4], af1[4];
  #pragma unroll
  for (int kt = 0; kt < 4; ++kt) {
    af0[kt] = *(const bf8*)(reps + (size_t)(r0 + l15)      * DP + kt * 32 + quad * 8);
    af1[kt] = *(const bf8*)(reps + (size_t)(r0 + 16 + l15) * DP + kt * 32 + quad * 8);
  }

  float rs0[4] = {0.f, 0.f, 0.f, 0.f};
  float rs1[4] = {0.f, 0.f, 0.f, 0.f};

  for (int t = 0; t < 8; ++t) {
    bf16_t* buf = Bs[t & 1];
    __syncthreads();                       // prev readers of buf done (t-2)
    const int jt0 = col0 + t * 64;
    #pragma unroll
    for (int r = 0; r < 4; ++r) {          // stage 16 KB: slot s -> 16 B
      const int s   = r * 256 + tid;
      const int col = s >> 4;              // 0..63
      const int cf  = (s & 15) ^ (col & 15);   // fetch chunk (XOR swizzle)
      const bf16_t* g = reps + (size_t)(jt0 + col) * DP + cf * 8;
      __builtin_amdgcn_global_load_lds(
          (const AS1 void*)g,
          (AS3 void*)(buf + (size_t)(r * 256 + wave * 64) * 8), 16, 0, 0);
    }
    __syncthreads();                       // vmcnt drained -> tile visible

    #pragma unroll
    for (int st = 0; st < 4; ++st) {
      const bf16_t* base = buf + (size_t)(st * 16 + l15) * DP;
      bf8 b0 = *(const bf8*)(base + (((0 * 4 + quad) ^ l15) * 8));
      bf8 b1 = *(const bf8*)(base + (((1 * 4 + quad) ^ l15) * 8));
      bf8 b2 = *(const bf8*)(base + (((2 * 4 + quad) ^ l15) * 8));
      bf8 b3 = *(const bf8*)(base + (((3 * 4 + quad) ^ l15) * 8));
      f32x4 acc0 = (f32x4){0.f, 0.f, 0.f, 0.f};
      f32x4 acc1 = (f32x4){0.f, 0.f, 0.f, 0.f};
      acc0 = mfma_16x16x32(af0[0], b0, acc0); acc1 = mfma_16x16x32(af1[0], b0, acc1);
      acc0 = mfma_16x16x32(af0[1], b1, acc0); acc1 = mfma_16x16x32(af1[1], b1, acc1);
      acc0 = mfma_16x16x32(af0[2], b2, acc0); acc1 = mfma_16x16x32(af1[2], b2, acc1);
      acc0 = mfma_16x16x32(af0[3], b3, acc0); acc1 = mfma_16x16x32(af1[3], b3, acc1);
      #pragma unroll
      for (int r = 0; r < 4; ++r) {
        rs0[r] += __builtin_amdgcn_exp2f(acc0[r] * SCALE_LOG2);
        rs1[r] += __builtin_amdgcn_exp2f(acc1[r] * SCALE_LOG2);
      }
    }
  }

  const int i0 = r0 + quad * 4;
  #pragma unroll
  for (int r = 0; r < 4; ++r) {
    float v = rs0[r];
    v += __shfl_xor(v, 1); v += __shfl_xor(v, 2);
    v += __shfl_xor(v, 4); v += __shfl_xor(v, 8);
    if (l15 == 0) atomicAdd(&S[i0 + r], v);
  }
  #pragma unroll
  for (int r = 0; r < 4; ++r) {
    float v = rs1[r];
    v += __shfl_xor(v, 1); v += __shfl_xor(v, 2);
    v += __shfl_xor(v, 4); v += __shfl_xor(v, 8);
    if (l15 == 0) atomicAdd(&S[i0 + 16 + r], v);
  }
}

// ---------------------------------------------------------------------------
// rowfinal: per-row loss correction + grid-wide mean via device-scope atomic
// finalize (last block writes d_out). 128 blocks x 256; wave handles 16 rows.
//   L_i = log(S_raw - exp(d_ii/t) + exp(pos/t)) - pos/t
// ---------------------------------------------------------------------------
__global__ __launch_bounds__(256) void rowfinal_kernel(
    const bf16_t* __restrict__ reps, const float* __restrict__ S,
    float* __restrict__ Lsum, int* __restrict__ cnt,
    float* __restrict__ out) {
  const int tid  = threadIdx.x;
  const int wave = tid >> 6;
  const int lane = tid & 63;
  float part = 0.f;
  #pragma unroll 1
  for (int i = 0; i < 16; ++i) {
    const int row = blockIdx.x * 64 + wave * 16 + i;
    bf16x2 a = *(const bf16x2*)(reps + (size_t)row * DP + lane * 2);
    bf16x2 b = *(const bf16x2*)(reps + (size_t)(row ^ B_ROWS) * DP + lane * 2);
    float a0 = (float)a.x, a1 = (float)a.y;
    float b0 = (float)b.x, b1 = (float)b.y;
    float dii = a0 * a0 + a1 * a1;
    float pos = a0 * b0 + a1 * b1;
    #pragma unroll
    for (int m = 1; m < 64; m <<= 1) {
      dii += __shfl_xor(dii, m);
      pos += __shfl_xor(pos, m);
    }
    if (lane == 0) {
      float Si = S[row] - __builtin_amdgcn_exp2f(dii * SCALE_LOG2)
                        + __builtin_amdgcn_exp2f(pos * SCALE_LOG2);
      part += logf(Si) - pos * INV_T;
    }
  }
  __shared__ float wpart[4];
  if (lane == 0) wpart[wave] = part;
  __syncthreads();
  if (tid == 0) {
    float bsum = wpart[0] + wpart[1] + wpart[2] + wpart[3];
    atomicAdd(Lsum, bsum);
    __threadfence();
    int old = __hip_atomic_fetch_add(cnt, 1, __ATOMIC_ACQ_REL,
                                     __HIP_MEMORY_SCOPE_AGENT);
    if (old == (int)gridDim.x - 1) {
      float tot = __hip_atomic_load(Lsum, __ATOMIC_RELAXED,
                                    __HIP_MEMORY_SCOPE_AGENT);
      out[0] = tot * (1.0f / NTOT);
    }
  }
}

// ---------------------------------------------------------------------------
extern "C" void kernel_launch(void* const* d_in, const int* in_sizes, int n_in,
                              void* d_out, int out_size, void* d_ws, size_t ws_size,
                              hipStream_t stream) {
  const float* x_img  = (const float*)d_in[0];
  const float* x_txt  = (const float*)d_in[1];
  const float* We_img = (const float*)d_in[2];
  const float* be_img = (const float*)d_in[3];
  const float* We_txt = (const float*)d_in[4];
  const float* be_txt = (const float*)d_in[5];
  const float* W1_img = (const float*)d_in[6];
  const float* b1_img = (const float*)d_in[7];
  const float* W2_img = (const float*)d_in[8];
  const float* b2_img = (const float*)d_in[9];
  const float* W1_txt = (const float*)d_in[10];
  const float* b1_txt = (const float*)d_in[11];
  const float* W2_txt = (const float*)d_in[12];
  const float* b2_txt = (const float*)d_in[13];

  char* p = (char*)d_ws;
  bf16_t* xbf_img = (bf16_t*)p; p += (size_t)B_ROWS * DIN * 2;
  bf16_t* xbf_txt = (bf16_t*)p; p += (size_t)B_ROWS * DIN * 2;
  bf16_t* Wet_img = (bf16_t*)p; p += (size_t)DENC * DIN * 2;
  bf16_t* Wet_txt = (bf16_t*)p; p += (size_t)DENC * DIN * 2;
  bf16_t* W1t_img = (bf16_t*)p; p += (size_t)DH * DENC * 2;
  bf16_t* W1t_txt = (bf16_t*)p; p += (size_t)DH * DENC * 2;
  bf16_t* W2t_img = (bf16_t*)p; p += (size_t)DP * DH * 2;
  bf16_t* W2t_txt = (bf16_t*)p; p += (size_t)DP * DH * 2;
  bf16_t* h_img   = (bf16_t*)p; p += (size_t)B_ROWS * DENC * 2;
  bf16_t* h_txt   = (bf16_t*)p; p += (size_t)B_ROWS * DENC * 2;
  bf16_t* g_img   = (bf16_t*)p; p += (size_t)B_ROWS * DH * 2;
  bf16_t* g_txt   = (bf16_t*)p; p += (size_t)B_ROWS * DH * 2;
  bf16_t* reps    = (bf16_t*)p; p += (size_t)NTOT * DP * 2;
  float*  S       = (float*) p; p += (size_t)NTOT * 4;
  float*  Lsum    = (float*) p; p += 4;
  int*    cnt     = (int*)   p; p += 4;

  // zero S + Lsum + cnt in one memset
  hipMemsetAsync(S, 0, (size_t)NTOT * 4 + 8, stream);

  prep_kernel<<<336 + 8192, 256, 0, stream>>>(
      x_img, x_txt, We_img, We_txt, W1_img, W1_txt, W2_img, W2_txt,
      xbf_img, xbf_txt, Wet_img, Wet_txt, W1t_img, W1t_txt, W2t_img, W2t_txt);

  // encoder: h = x @ We + be   [4096x512], K=1024 (img & txt via z)
  gemm_glds<128, false><<<dim3(DENC / 64, B_ROWS / 128, 2), 256, 0, stream>>>(
      xbf_img, xbf_txt, Wet_img, Wet_txt, be_img, be_txt, h_img, h_txt,
      DENC, DIN);
  // head 1: g = relu(h @ W1 + b1)   [4096x256], K=512
  gemm_glds<64, true><<<dim3(DH / 64, B_ROWS / 64, 2), 256, 0, stream>>>(
      h_img, h_txt, W1t_img, W1t_txt, b1_img, b1_txt, g_img, g_txt,
      DH, DENC);
  // head 2 + normalize fused -> reps bf16 [8192x128]
  head2_norm<<<dim3(B_ROWS / 64, 1, 2), 256, 0, stream>>>(
      g_img, g_txt, W2t_img, W2t_txt, b2_img, b2_txt, reps);

  sim_rowsum_kernel<<<dim3(16, NTOT / 128), 256, 0, stream>>>(reps, S);
  rowfinal_kernel<<<NTOT / 64, 256, 0, stream>>>(reps, S, Lsum, cnt,
                                                 (float*)d_out);
}